// Round 14
// baseline (254.408 us; speedup 1.0000x reference)
//
#include <hip/hip_runtime.h>
#include <cmath>

#define DIM 16
#define VOCAB 18
#define TLEN 2048
#define NBLK (TLEN / 64)
#define WPAD 17  // padded wtab row stride (bank spread)

// Load float input element idx, from either a bf16 or f32 device buffer.
__device__ __forceinline__ float ldf(const void* p, int idx, int isbf) {
    if (isbf) {
        unsigned int w = ((const unsigned short*)p)[idx];
        return __uint_as_float(w << 16);
    }
    return ((const float*)p)[idx];
}

// ---------------------------------------------------------------------------
// Detector 1: token width. int64 tokens (0..17) have all odd 32-bit words 0.
// flag[0] <- 1 if int64, 0 if int32.
// ---------------------------------------------------------------------------
__global__ void detect_tok(const int* __restrict__ x32, int* __restrict__ flag) {
    int v = 0;
    for (int j = threadIdx.x; j < 4096; j += 64) v |= x32[2 * j + 1];
    unsigned long long any = __ballot(v != 0);
    if (threadIdx.x == 0) flag[0] = (any == 0ULL) ? 1 : 0;
}

// ---------------------------------------------------------------------------
// Detector 2: float width. bf16 words of N(0,1) data have exponent in
// [90,140]; f32 lo-mantissa words are uniform random -> certain failure.
// flag[1] <- 1 if bf16, 0 if f32.
// ---------------------------------------------------------------------------
__global__ void detect_f(const unsigned short* __restrict__ emb16,
                         int* __restrict__ flag) {
    int bad = 0;
    for (int j = threadIdx.x; j < VOCAB * DIM; j += 64) {
        unsigned short w = emb16[j];
        int e = (w >> 7) & 0xFF;
        if (!((e >= 90 && e <= 140) || (w & 0x7FFF) == 0)) bad = 1;
    }
    unsigned long long anybad = __ballot(bad);
    if (threadIdx.x == 0) flag[1] = (anybad == 0ULL) ? 1 : 0;
}

// ---------------------------------------------------------------------------
// Setup: wtab[v][k] = sum_d emb[v,d] * W_w[k,d] + W_b[k]   (18 x 16, f32)
// ---------------------------------------------------------------------------
__global__ void wtab_kernel(const void* __restrict__ emb,
                            const void* __restrict__ W_w,
                            const void* __restrict__ W_b,
                            const int* __restrict__ flag,
                            float* __restrict__ wtab) {
    int tid = threadIdx.x;
    int isbf = flag[1];
    if (tid < VOCAB * DIM) {
        int v = tid >> 4, kk = tid & 15;
        float s = ldf(W_b, kk, isbf);
#pragma unroll
        for (int d = 0; d < DIM; ++d)
            s = fmaf(ldf(emb, v * DIM + d, isbf), ldf(W_w, kk * DIM + d, isbf), s);
        wtab[tid] = s;
    }
}

// DPP row-rotate (within 16-lane rows), compile-time control 0x120|N.
template <int CTRL>
__device__ __forceinline__ float ror_f(float v) {
    return __int_as_float(
        __builtin_amdgcn_mov_dpp(__float_as_int(v), CTRL, 0xF, 0xF, true));
}

#define TWO_LOG2E 2.8853900817779268f  // 2*log2(e)

// tanh from a pre-scaled argument S = 2*log2(e)*x.
__device__ __forceinline__ float tanh_scaled(float S) {
    float e2 = __builtin_amdgcn_exp2f(S);
    float r = __builtin_amdgcn_rcpf(e2 + 1.0f);
    return fmaf(-2.0f, r, 1.0f);
}

// Sum across the lane<->lane+32 pair (both lanes get the full sum).
__device__ __forceinline__ float pair_sum32(float p) {
#if __has_builtin(__builtin_amdgcn_permlane32_swap)
    typedef int i32x2 __attribute__((ext_vector_type(2)));
    i32x2 sw = __builtin_amdgcn_permlane32_swap(__float_as_int(p),
                                                __float_as_int(p), false, false);
    return __int_as_float(sw.x) + __int_as_float(sw.y);
#else
    return p + __shfl_xor(p, 32, 64);
#endif
}

// ---------------------------------------------------------------------------
// Main RNN kernel. 32 lanes per batch element: lane (row r, col k) owns
// output dim k and the 8 dot-terms d = (k + (j + 8*(r>>1))*c) & 15, j=0..7.
// Rows 0,1 = elements A,B half-0; rows 2,3 = elements A,B half-1 (base
// pre-rotated ror:8). Halves summed via permlane32_swap (lane i <-> i+32).
// 512 threads/block = 8 waves = 16 elements; 256 blocks; 2 waves/SIMD.
// ---------------------------------------------------------------------------
__global__ __launch_bounds__(512) void rnn_kernel(const int* __restrict__ x32,
                                                  const int* __restrict__ flag,
                                                  const float* __restrict__ wtab_g,
                                                  const void* __restrict__ U_w,
                                                  const void* __restrict__ head_w,
                                                  const void* __restrict__ head_b,
                                                  float* __restrict__ out) {
    __shared__ float lds_wtab[VOCAB * WPAD];
    __shared__ float sU[DIM * DIM];
    __shared__ float lds_h[16][DIM];
    __shared__ int lds_tok[2][16][68];

    const int tid = threadIdx.x;
    const int is64 = __builtin_amdgcn_readfirstlane(flag[0]);
    const int isbf = __builtin_amdgcn_readfirstlane(flag[1]);

    // Strided fills (never the guarded-single-store 288>256 bug again).
    for (int i = tid; i < VOCAB * DIM; i += 512)
        lds_wtab[(i >> 4) * WPAD + (i & 15)] = wtab_g[i] * TWO_LOG2E;
    for (int i = tid; i < DIM * DIM; i += 512) sU[i] = ldf(U_w, i, isbf);

    const int lane = tid & 63;
    const int wave = tid >> 6;
    const int row = lane >> 4;             // 0..3
    const int k = lane & 15;               // output dim owned by this lane
    const int half = row >> 1;             // 0: d-terms j=0..7; 1: j=8..15
    const int e = (wave << 1) | (row & 1); // element within block (0..15)
    const int lo32 = (lane < 32);

    // Probe DPP ror direction: after ror:1, lane k holds id of lane (k+c)&15.
    int p = __builtin_amdgcn_mov_dpp(k, 0x121, 0xF, 0xF, true);
    int c = (p - k) & 15;

#define STAGE(B, BUF)                                                           \
    for (int i = tid; i < 1024; i += 512) {                                     \
        int ee = i >> 6, s = i & 63;                                            \
        size_t idx = (size_t)((blockIdx.x << 4) | ee) * TLEN + ((B) << 6) + s;  \
        lds_tok[BUF][ee][s] = is64 ? x32[idx << 1] : x32[idx];                  \
    }

    STAGE(0, 0)
    __syncthreads();  // covers lds_wtab/sU fills and block-0 tokens

    // Pre-rotated, pre-scaled U for this lane's 8 dot-terms.
    float ur[8];
#pragma unroll
    for (int j = 0; j < 8; ++j)
        ur[j] = sU[(k << 4) | ((k + (j + 8 * half) * c) & 15)] * TWO_LOG2E;

    float h = 0.0f;

    for (int blk = 0; blk < NBLK; ++blk) {
        const int cb = blk & 1, nb = cb ^ 1;
        if (blk + 1 < NBLK) {
            STAGE(blk + 1, nb)
        }
        __syncthreads();  // next-blk tokens staged; prev readers done

        const int(*cur)[68] = lds_tok[cb];
        const int(*nxt)[68] = lds_tok[nb];

        // 2-stage pipeline: t1 = token for step s+1, w = wtab val for step s.
        int t1 = cur[e][1];
        float w = lds_wtab[cur[e][0] * WPAD + k];

#pragma unroll
        for (int s = 0; s < 64; ++s) {
            float wn = lds_wtab[t1 * WPAD + k];                  // for s+1
            int t2 = (s < 62) ? cur[e][s + 2] : nxt[e][s - 62];  // for s+2

            // Base: rows 0,1 use h; rows 2,3 use ror:8(h) (offset +8 mod 16
            // regardless of direction c since 8*c = 8 mod 16).
            float r8 = ror_f<0x128>(h);
            float b = lo32 ? h : r8;

            float r1 = ror_f<0x121>(b);
            float r2 = ror_f<0x122>(b);
            float r3 = ror_f<0x123>(b);
            float r4 = ror_f<0x124>(b);
            float r5 = ror_f<0x125>(b);
            float r6 = ror_f<0x126>(b);
            float r7 = ror_f<0x127>(b);

            float a0 = fmaf(ur[0], b, lo32 ? w : 0.0f);
            float a1 = ur[1] * r1;
            a0 = fmaf(ur[2], r2, a0);
            a1 = fmaf(ur[3], r3, a1);
            a0 = fmaf(ur[4], r4, a0);
            a1 = fmaf(ur[5], r5, a1);
            a0 = fmaf(ur[6], r6, a0);
            a1 = fmaf(ur[7], r7, a1);

            h = tanh_scaled(pair_sum32(a0 + a1));
            w = wn;
            t1 = t2;
        }
        __syncthreads();  // readers of cur done before it is restaged
    }

    // Head: out[b,v] = h . head_w[v,:] + head_b[v], f32 store.
    if (lo32) lds_h[e][k] = h;
    __syncthreads();

    for (int i = tid; i < 16 * VOCAB; i += 512) {
        int ee = i / VOCAB;
        int v = i - ee * VOCAB;
        float s = ldf(head_b, v, isbf);
#pragma unroll
        for (int d = 0; d < DIM; ++d)
            s = fmaf(lds_h[ee][d], ldf(head_w, (v << 4) + d, isbf), s);
        out[(size_t)((blockIdx.x << 4) | ee) * VOCAB + v] = s;
    }
}

extern "C" void kernel_launch(void* const* d_in, const int* in_sizes, int n_in,
                              void* d_out, int out_size, void* d_ws, size_t ws_size,
                              hipStream_t stream) {
    const int* x = (const int*)d_in[0];
    const void* emb = d_in[1];
    const void* W_w = d_in[2];
    const void* W_b = d_in[3];
    const void* U_w = d_in[4];
    const void* head_w = d_in[5];
    const void* head_b = d_in[6];

    float* wtab = (float*)d_ws;              // 288 floats
    int* flag = (int*)((char*)d_ws + 4096);  // [0]=tok is64, [1]=floats are bf16

    detect_tok<<<1, 64, 0, stream>>>(x, flag);
    detect_f<<<1, 64, 0, stream>>>((const unsigned short*)emb, flag);
    wtab_kernel<<<1, 320, 0, stream>>>(emb, W_w, W_b, flag, wtab);
    rnn_kernel<<<256, 512, 0, stream>>>(x, flag, wtab, U_w, head_w, head_b,
                                        (float*)d_out);
}

// Round 16
// 238.797 us; speedup vs baseline: 1.0654x; 1.0654x over previous
//
#include <hip/hip_runtime.h>
#include <cmath>

#define DIM 16
#define VOCAB 18
#define TLEN 2048
#define NBLK (TLEN / 64)
#define TWO_LOG2E 2.8853900817779268f  // 2*log2(e)

// Load float input element idx, from either a bf16 or f32 device buffer.
__device__ __forceinline__ float ldf(const void* p, int idx, int isbf) {
    if (isbf) {
        unsigned int w = ((const unsigned short*)p)[idx];
        return __uint_as_float(w << 16);
    }
    return ((const float*)p)[idx];
}

// ---------------------------------------------------------------------------
// Detector 1: token width. int64 tokens (0..17) have all odd 32-bit words 0.
// ---------------------------------------------------------------------------
__global__ void detect_tok(const int* __restrict__ x32, int* __restrict__ flag) {
    int v = 0;
    for (int j = threadIdx.x; j < 4096; j += 64) v |= x32[2 * j + 1];
    unsigned long long any = __ballot(v != 0);
    if (threadIdx.x == 0) flag[0] = (any == 0ULL) ? 1 : 0;
}

// ---------------------------------------------------------------------------
// Detector 2: float width. bf16 words of N(0,1) data have exponent in
// [90,140]; f32 lo-mantissa words are uniform random -> certain failure.
// ---------------------------------------------------------------------------
__global__ void detect_f(const unsigned short* __restrict__ emb16,
                         int* __restrict__ flag) {
    int bad = 0;
    for (int j = threadIdx.x; j < VOCAB * DIM; j += 64) {
        unsigned short w = emb16[j];
        int e = (w >> 7) & 0xFF;
        if (!((e >= 90 && e <= 140) || (w & 0x7FFF) == 0)) bad = 1;
    }
    unsigned long long anybad = __ballot(bad);
    if (threadIdx.x == 0) flag[1] = (anybad == 0ULL) ? 1 : 0;
}

// ---------------------------------------------------------------------------
// Setup: wtab[v][k] = sum_d emb[v,d] * W_w[k,d] + W_b[k]   (18 x 16, f32)
// ---------------------------------------------------------------------------
__global__ void wtab_kernel(const void* __restrict__ emb,
                            const void* __restrict__ W_w,
                            const void* __restrict__ W_b,
                            const int* __restrict__ flag,
                            float* __restrict__ wtab) {
    int tid = threadIdx.x;
    int isbf = flag[1];
    if (tid < VOCAB * DIM) {
        int v = tid >> 4, kk = tid & 15;
        float s = ldf(W_b, kk, isbf);
#pragma unroll
        for (int d = 0; d < DIM; ++d)
            s = fmaf(ldf(emb, v * DIM + d, isbf), ldf(W_w, kk * DIM + d, isbf), s);
        wtab[tid] = s;
    }
}

// DPP row-rotate (within 16-lane rows), compile-time control 0x120|N.
template <int CTRL>
__device__ __forceinline__ float ror_f(float v) {
    return __int_as_float(
        __builtin_amdgcn_mov_dpp(__float_as_int(v), CTRL, 0xF, 0xF, true));
}

// tanh from a pre-scaled argument S = 2*log2(e)*x.
__device__ __forceinline__ float tanh_scaled(float S) {
    float e2 = __builtin_amdgcn_exp2f(S);
    float r = __builtin_amdgcn_rcpf(e2 + 1.0f);
    return fmaf(-2.0f, r, 1.0f);
}

// Sum across the lane<->lane+32 pair (both lanes get the full sum).
__device__ __forceinline__ float pair_sum32(float p) {
#if __has_builtin(__builtin_amdgcn_permlane32_swap)
    typedef int i32x2 __attribute__((ext_vector_type(2)));
    i32x2 sw = __builtin_amdgcn_permlane32_swap(__float_as_int(p),
                                                __float_as_int(p), false, false);
    return __int_as_float(sw.x) + __int_as_float(sw.y);
#else
    return p + __shfl_xor(p, 32, 64);
#endif
}

#define WZLEN 600  // wtabT: 16 real rows (0..287), zeros (288..599), hi base +297

// ---------------------------------------------------------------------------
// Main RNN kernel. 32 lanes per batch element (R14-validated layout):
// lane (row r, col k): rows 0,1 = elems A,B terms 0-7; rows 2,3 = A,B terms
// 8-15 (base ror:8). Halves summed via permlane32_swap.
// Tokens in wave-private registers: 4 tokens/lane (64/blk per 16-lane group
// — R15 BUG was 2/lane = 32), broadcast via __shfl(., s>>2, 16), slot s&3.
// Transposed zero-row wtab: hi lanes read w=0 (no cndmask).
// 512 thr/block, 256 blocks -> 2048 free-running waves = 2/SIMD.
// ---------------------------------------------------------------------------
__global__ __launch_bounds__(512) void rnn_kernel(const int* __restrict__ x32,
                                                  const int* __restrict__ flag,
                                                  const float* __restrict__ wtab_g,
                                                  const void* __restrict__ U_w,
                                                  const void* __restrict__ head_w,
                                                  const void* __restrict__ head_b,
                                                  float* __restrict__ out) {
    __shared__ float wtabT[WZLEN];  // [dim 0..15][tok] transposed; rest zeros
    __shared__ float sU[DIM * DIM];
    __shared__ float lds_h[16][DIM];

    const int tid = threadIdx.x;
    const int is64 = __builtin_amdgcn_readfirstlane(flag[0]);
    const int isbf = __builtin_amdgcn_readfirstlane(flag[1]);

    // Strided fills (never the guarded-single-store bug again).
    for (int i = tid; i < WZLEN; i += 512) {
        float val = 0.0f;
        if (i < 16 * VOCAB) {
            int r = i / VOCAB, v = i - r * VOCAB;
            val = wtab_g[v * DIM + r] * TWO_LOG2E;  // transposed: [k][v]
        }
        wtabT[i] = val;
    }
    for (int i = tid; i < DIM * DIM; i += 512) sU[i] = ldf(U_w, i, isbf);
    __syncthreads();  // last block-wide barrier until the head

    const int lane = tid & 63;
    const int wave = tid >> 6;
    const int row = lane >> 4;              // 0..3
    const int k = lane & 15;                // output dim owned by this lane
    const int half = row >> 1;              // 0: terms 0-7; 1: terms 8-15
    const int e = (wave << 1) | (row & 1);  // element within block
    const bool lo32 = (lane < 32);
    const int gelem = (blockIdx.x << 4) | e;

    // Probe DPP ror direction (validated R12-R14).
    int p = __builtin_amdgcn_mov_dpp(k, 0x121, 0xF, 0xF, true);
    int c = (p - k) & 15;

    // Pre-rotated, pre-scaled U for this lane's 8 dot-terms.
    float ur[8];
#pragma unroll
    for (int j = 0; j < 8; ++j)
        ur[j] = sU[(k << 4) | ((k + (j + 8 * half) * c) & 15)] * TWO_LOG2E;

    // wtab row base (float index): lo half -> real row k; hi half -> zeros.
    const int wb = k * VOCAB + half * 297;

    // Lane's token slots: steps 4k .. 4k+3 of each 64-step blk.
    const size_t tokbase = (size_t)gelem * TLEN + (k << 2);

    int cur0, cur1, cur2, cur3, nxt0, nxt1, nxt2, nxt3;
#define LOADTOK(T0, T1, T2, T3, B)                                            \
    if (is64) {                                                               \
        const int* pp = x32 + ((tokbase + ((size_t)(B) << 6)) << 1);          \
        int4 a = *(const int4*)pp;                                            \
        int4 bq = *(const int4*)(pp + 4);                                     \
        T0 = a.x; T1 = a.z; T2 = bq.x; T3 = bq.z;                             \
    } else {                                                                  \
        int4 a = *(const int4*)(x32 + tokbase + ((size_t)(B) << 6));          \
        T0 = a.x; T1 = a.y; T2 = a.z; T3 = a.w;                               \
    }

    LOADTOK(cur0, cur1, cur2, cur3, 0)
    float h = 0.0f;

    // Pipeline primer: token/w for step 0.
    int tk = __shfl(cur0, 0, 16);
    float w = wtabT[wb + tk];

    for (int b = 0; b < NBLK; ++b) {
        const int nb = (b + 1 < NBLK) ? b + 1 : b;
        LOADTOK(nxt0, nxt1, nxt2, nxt3, nb)  // lands during compute below

#pragma unroll
        for (int s = 0; s < 64; ++s) {
            // Next step's token (regs, compile-time slot/lane) + wtab value.
            const int tn = s + 1;
            int tk2 = (s < 63)
                          ? __shfl((tn & 3) == 0   ? cur0
                                   : (tn & 3) == 1 ? cur1
                                   : (tn & 3) == 2 ? cur2
                                                   : cur3,
                                   tn >> 2, 16)
                          : __shfl(nxt0, 0, 16);
            float wn = wtabT[wb + tk2];

            float r8 = ror_f<0x128>(h);
            float bb = lo32 ? h : r8;  // base: terms 0-7 use h; 8-15 use ror8
            float r1 = ror_f<0x121>(bb);
            float r2 = ror_f<0x122>(bb);
            float r3 = ror_f<0x123>(bb);
            float r4 = ror_f<0x124>(bb);
            float r5 = ror_f<0x125>(bb);
            float r6 = ror_f<0x126>(bb);
            float r7 = ror_f<0x127>(bb);

            float a0 = fmaf(ur[0], bb, w);  // w = 0 for hi half via zero rows
            float a1 = ur[1] * r1;
            a0 = fmaf(ur[2], r2, a0);
            a1 = fmaf(ur[3], r3, a1);
            a0 = fmaf(ur[4], r4, a0);
            a1 = fmaf(ur[5], r5, a1);
            a0 = fmaf(ur[6], r6, a0);
            a1 = fmaf(ur[7], r7, a1);

            h = tanh_scaled(pair_sum32(a0 + a1));
            w = wn;
        }
        cur0 = nxt0;
        cur1 = nxt1;
        cur2 = nxt2;
        cur3 = nxt3;
    }

    // Head: out[b,v] = h . head_w[v,:] + head_b[v], f32 store.
    if (lo32) lds_h[e][k] = h;
    __syncthreads();

    for (int i = tid; i < 16 * VOCAB; i += 512) {
        int ee = i / VOCAB;
        int v = i - ee * VOCAB;
        float s = ldf(head_b, v, isbf);
#pragma unroll
        for (int d = 0; d < DIM; ++d)
            s = fmaf(lds_h[ee][d], ldf(head_w, (v << 4) + d, isbf), s);
        out[(size_t)((blockIdx.x << 4) | ee) * VOCAB + v] = s;
    }
}

extern "C" void kernel_launch(void* const* d_in, const int* in_sizes, int n_in,
                              void* d_out, int out_size, void* d_ws, size_t ws_size,
                              hipStream_t stream) {
    const int* x = (const int*)d_in[0];
    const void* emb = d_in[1];
    const void* W_w = d_in[2];
    const void* W_b = d_in[3];
    const void* U_w = d_in[4];
    const void* head_w = d_in[5];
    const void* head_b = d_in[6];

    float* wtab = (float*)d_ws;              // 288 floats
    int* flag = (int*)((char*)d_ws + 4096);  // [0]=tok is64, [1]=floats are bf16

    detect_tok<<<1, 64, 0, stream>>>(x, flag);
    detect_f<<<1, 64, 0, stream>>>((const unsigned short*)emb, flag);
    wtab_kernel<<<1, 320, 0, stream>>>(emb, W_w, W_b, flag, wtab);
    rnn_kernel<<<256, 512, 0, stream>>>(x, flag, wtab, U_w, head_w, head_b,
                                        (float*)d_out);
}

// Round 17
// 218.950 us; speedup vs baseline: 1.1619x; 1.0906x over previous
//
#include <hip/hip_runtime.h>
#include <cmath>

#define DIM 16
#define VOCAB 18
#define TLEN 2048
#define NBLK (TLEN / 64)
#define TWO_LOG2E 2.8853900817779268f  // 2*log2(e)

// Load float input element idx, from either a bf16 or f32 device buffer.
__device__ __forceinline__ float ldf(const void* p, int idx, int isbf) {
    if (isbf) {
        unsigned int w = ((const unsigned short*)p)[idx];
        return __uint_as_float(w << 16);
    }
    return ((const float*)p)[idx];
}

// ---------------------------------------------------------------------------
// Detector 1: token width. int64 tokens (0..17) have all odd 32-bit words 0.
// ---------------------------------------------------------------------------
__global__ void detect_tok(const int* __restrict__ x32, int* __restrict__ flag) {
    int v = 0;
    for (int j = threadIdx.x; j < 4096; j += 64) v |= x32[2 * j + 1];
    unsigned long long any = __ballot(v != 0);
    if (threadIdx.x == 0) flag[0] = (any == 0ULL) ? 1 : 0;
}

// ---------------------------------------------------------------------------
// Detector 2: float width. bf16 words of N(0,1) data have exponent in
// [90,140]; f32 lo-mantissa words are uniform random -> certain failure.
// ---------------------------------------------------------------------------
__global__ void detect_f(const unsigned short* __restrict__ emb16,
                         int* __restrict__ flag) {
    int bad = 0;
    for (int j = threadIdx.x; j < VOCAB * DIM; j += 64) {
        unsigned short w = emb16[j];
        int e = (w >> 7) & 0xFF;
        if (!((e >= 90 && e <= 140) || (w & 0x7FFF) == 0)) bad = 1;
    }
    unsigned long long anybad = __ballot(bad);
    if (threadIdx.x == 0) flag[1] = (anybad == 0ULL) ? 1 : 0;
}

// ---------------------------------------------------------------------------
// Setup: wtab[v][k] = sum_d emb[v,d] * W_w[k,d] + W_b[k]   (18 x 16, f32)
// ---------------------------------------------------------------------------
__global__ void wtab_kernel(const void* __restrict__ emb,
                            const void* __restrict__ W_w,
                            const void* __restrict__ W_b,
                            const int* __restrict__ flag,
                            float* __restrict__ wtab) {
    int tid = threadIdx.x;
    int isbf = flag[1];
    if (tid < VOCAB * DIM) {
        int v = tid >> 4, kk = tid & 15;
        float s = ldf(W_b, kk, isbf);
#pragma unroll
        for (int d = 0; d < DIM; ++d)
            s = fmaf(ldf(emb, v * DIM + d, isbf), ldf(W_w, kk * DIM + d, isbf), s);
        wtab[tid] = s;
    }
}

// DPP row-rotate (within 16-lane rows), compile-time control 0x120|N.
template <int CTRL>
__device__ __forceinline__ float ror_f(float v) {
    return __int_as_float(
        __builtin_amdgcn_mov_dpp(__float_as_int(v), CTRL, 0xF, 0xF, true));
}

// Sum across the lane<->lane+32 pair (both lanes get the full sum).
__device__ __forceinline__ float pair_sum32(float p) {
#if __has_builtin(__builtin_amdgcn_permlane32_swap)
    typedef int i32x2 __attribute__((ext_vector_type(2)));
    i32x2 sw = __builtin_amdgcn_permlane32_swap(__float_as_int(p),
                                                __float_as_int(p), false, false);
    return __int_as_float(sw.x) + __int_as_float(sw.y);
#else
    return p + __shfl_xor(p, 32, 64);
#endif
}

#define WZLEN 600  // wtabT: 16 real rows (0..287), zeros (288..599), hi base +297

// ---------------------------------------------------------------------------
// Main RNN kernel (R14/R16-validated 32-lane layout; folded-state variant).
// State r = 1/(2^S+1) (h = 1-2r folded into weights/const table):
//   S = scale*(wtab[tok][k]+rowsumU[k]) + sum_j (-2*scale*U[k][dj]) * r[dj]
// lane (row,k): rows 0,1 = elems A,B terms 0-7; rows 2,3 = terms 8-15
// (base ror:8 + cndmask). Halves summed via permlane32_swap.
// Tokens: wave-private double-buffered LDS slab, ds_read at imm offsets
// (broadcast, no barriers); token read 4 ahead, wtab value 2 ahead.
// 512 thr/block, 256 blocks -> 2 waves/SIMD, free-running.
// ---------------------------------------------------------------------------
__global__ __launch_bounds__(512) void rnn_kernel(const int* __restrict__ x32,
                                                  const int* __restrict__ flag,
                                                  const float* __restrict__ wtab_g,
                                                  const void* __restrict__ U_w,
                                                  const void* __restrict__ head_w,
                                                  const void* __restrict__ head_b,
                                                  float* __restrict__ out) {
    __shared__ float wtabT[WZLEN];  // [k][v] + rowsum, prescaled; rest zeros
    __shared__ float sU[DIM * DIM];
    __shared__ float lds_h[16][DIM];
    __shared__ int slab[2][16][64];  // token slabs, wave-private slices

    const int tid = threadIdx.x;
    const int is64 = __builtin_amdgcn_readfirstlane(flag[0]);
    const int isbf = __builtin_amdgcn_readfirstlane(flag[1]);

    // Strided fills (never the guarded-single-store bug again).
    for (int i = tid; i < WZLEN; i += 512) {
        float val = 0.0f;
        if (i < 16 * VOCAB) {
            int r = i / VOCAB, v = i - r * VOCAB;
            float rs = 0.0f;
#pragma unroll
            for (int d = 0; d < DIM; ++d) rs += ldf(U_w, r * DIM + d, isbf);
            val = (wtab_g[v * DIM + r] + rs) * TWO_LOG2E;  // transposed + folded
        }
        wtabT[i] = val;
    }
    for (int i = tid; i < DIM * DIM; i += 512) sU[i] = ldf(U_w, i, isbf);
    __syncthreads();  // the only block-wide barrier until the head

    const int lane = tid & 63;
    const int wave = tid >> 6;
    const int row = lane >> 4;              // 0..3
    const int k = lane & 15;                // output dim owned by this lane
    const int half = row >> 1;              // 0: terms 0-7; 1: terms 8-15
    const int e = (wave << 1) | (row & 1);  // element within block
    const bool lo32 = (lane < 32);
    const int gelem = (blockIdx.x << 4) | e;

    // Probe DPP ror direction (validated R12-R16).
    int p = __builtin_amdgcn_mov_dpp(k, 0x121, 0xF, 0xF, true);
    int c = (p - k) & 15;

    // ur2[j] = -2 * scale * U[k][(k + (j + 8*half)*c) & 15].
    float ur2[8];
#pragma unroll
    for (int j = 0; j < 8; ++j)
        ur2[j] = sU[(k << 4) | ((k + (j + 8 * half) * c) & 15)] *
                 (-2.0f * TWO_LOG2E);

    // wtab row base (float idx): lo half -> real row k; hi half -> zeros.
    const int wb = k * VOCAB + half * 297;

    // Lane's token slots in global: steps 4k..4k+3 of each 64-step blk.
    const size_t tokbase = (size_t)gelem * TLEN + (k << 2);

    int* cur = &slab[0][e][0];
    int* nxt = &slab[1][e][0];

    int4 g;
#define LOADG(G, B)                                                           \
    if (lo32) {                                                               \
        if (is64) {                                                           \
            const int* pp = x32 + ((tokbase + ((size_t)(B) << 6)) << 1);      \
            int4 a = *(const int4*)pp;                                        \
            int4 bq = *(const int4*)(pp + 4);                                 \
            G = make_int4(a.x, a.z, bq.x, bq.z);                              \
        } else {                                                              \
            G = *(const int4*)(x32 + tokbase + ((size_t)(B) << 6));           \
        }                                                                     \
    }

    // Prologue: slab0 <- blk0; gcur <- blk1; prime pipeline regs.
    LOADG(g, 0)
    if (lo32) *(int4*)(cur + (k << 2)) = g;
    int4 gcur;
    LOADG(gcur, 1)

    int tk0 = cur[0], tk1 = cur[1];
    int t2 = cur[2], t3 = cur[3];
    float w0 = wtabT[wb + tk0], w1 = wtabT[wb + tk1];

    float rst = 0.5f;  // r-state for h0 = 0

    for (int b = 0; b < NBLK; ++b) {
        // Write next slab from gcur (loaded one blk ago), refill gcur.
        if (lo32) *(int4*)(nxt + (k << 2)) = gcur;
        const int nb2 = (b + 2 < NBLK) ? b + 2 : NBLK - 1;
        LOADG(gcur, nb2)

#pragma unroll
        for (int s = 0; s < 64; ++s) {
            // Token 4 ahead (imm-offset broadcast read), wtab value 2 ahead.
            int t4 = (s + 4 < 64) ? cur[s + 4] : nxt[s - 60];
            float w2 = wtabT[wb + t2];

            float r8 = ror_f<0x128>(rst);
            float bb = lo32 ? rst : r8;  // terms 0-7 use r; 8-15 use ror8(r)
            float r1 = ror_f<0x121>(bb);
            float r2 = ror_f<0x122>(bb);
            float r3 = ror_f<0x123>(bb);
            float r4 = ror_f<0x124>(bb);
            float r5 = ror_f<0x125>(bb);
            float r6 = ror_f<0x126>(bb);
            float r7 = ror_f<0x127>(bb);

            float a0 = fmaf(ur2[0], bb, w0);  // w0 = 0 for hi half (zero rows)
            float a1 = ur2[1] * r1;
            a0 = fmaf(ur2[2], r2, a0);
            a1 = fmaf(ur2[3], r3, a1);
            a0 = fmaf(ur2[4], r4, a0);
            a1 = fmaf(ur2[5], r5, a1);
            a0 = fmaf(ur2[6], r6, a0);
            a1 = fmaf(ur2[7], r7, a1);

            float S = pair_sum32(a0 + a1);
            rst = __builtin_amdgcn_rcpf(__builtin_amdgcn_exp2f(S) + 1.0f);

            w0 = w1;
            w1 = w2;
            t2 = t3;
            t3 = t4;
        }
        int* tmp = cur;
        cur = nxt;
        nxt = tmp;
    }

    // Head: h = 1 - 2r; out[b,v] = h . head_w[v,:] + head_b[v], f32 store.
    if (lo32) lds_h[e][k] = fmaf(-2.0f, rst, 1.0f);
    __syncthreads();

    for (int i = tid; i < 16 * VOCAB; i += 512) {
        int ee = i / VOCAB;
        int v = i - ee * VOCAB;
        float s = ldf(head_b, v, isbf);
#pragma unroll
        for (int d = 0; d < DIM; ++d)
            s = fmaf(lds_h[ee][d], ldf(head_w, (v << 4) + d, isbf), s);
        out[(size_t)((blockIdx.x << 4) | ee) * VOCAB + v] = s;
    }
}

extern "C" void kernel_launch(void* const* d_in, const int* in_sizes, int n_in,
                              void* d_out, int out_size, void* d_ws, size_t ws_size,
                              hipStream_t stream) {
    const int* x = (const int*)d_in[0];
    const void* emb = d_in[1];
    const void* W_w = d_in[2];
    const void* W_b = d_in[3];
    const void* U_w = d_in[4];
    const void* head_w = d_in[5];
    const void* head_b = d_in[6];

    float* wtab = (float*)d_ws;              // 288 floats
    int* flag = (int*)((char*)d_ws + 4096);  // [0]=tok is64, [1]=floats are bf16

    detect_tok<<<1, 64, 0, stream>>>(x, flag);
    detect_f<<<1, 64, 0, stream>>>((const unsigned short*)emb, flag);
    wtab_kernel<<<1, 320, 0, stream>>>(emb, W_w, W_b, flag, wtab);
    rnn_kernel<<<256, 512, 0, stream>>>(x, flag, wtab, U_w, head_w, head_b,
                                        (float*)d_out);
}

// Round 18
// 188.442 us; speedup vs baseline: 1.3501x; 1.1619x over previous
//
#include <hip/hip_runtime.h>
#include <cmath>

#define DIM 16
#define VOCAB 18
#define TLEN 2048
#define NBLK (TLEN / 64)
#define TWO_LOG2E 2.8853900817779268f  // 2*log2(e)

// Load float input element idx, from either a bf16 or f32 device buffer.
__device__ __forceinline__ float ldf(const void* p, int idx, int isbf) {
    if (isbf) {
        unsigned int w = ((const unsigned short*)p)[idx];
        return __uint_as_float(w << 16);
    }
    return ((const float*)p)[idx];
}

// ---------------------------------------------------------------------------
// Detector 1: token width. int64 tokens (0..17) have all odd 32-bit words 0.
// ---------------------------------------------------------------------------
__global__ void detect_tok(const int* __restrict__ x32, int* __restrict__ flag) {
    int v = 0;
    for (int j = threadIdx.x; j < 4096; j += 64) v |= x32[2 * j + 1];
    unsigned long long any = __ballot(v != 0);
    if (threadIdx.x == 0) flag[0] = (any == 0ULL) ? 1 : 0;
}

// ---------------------------------------------------------------------------
// Detector 2: float width. bf16 words of N(0,1) data have exponent in
// [90,140]; f32 lo-mantissa words are uniform random -> certain failure.
// ---------------------------------------------------------------------------
__global__ void detect_f(const unsigned short* __restrict__ emb16,
                         int* __restrict__ flag) {
    int bad = 0;
    for (int j = threadIdx.x; j < VOCAB * DIM; j += 64) {
        unsigned short w = emb16[j];
        int e = (w >> 7) & 0xFF;
        if (!((e >= 90 && e <= 140) || (w & 0x7FFF) == 0)) bad = 1;
    }
    unsigned long long anybad = __ballot(bad);
    if (threadIdx.x == 0) flag[1] = (anybad == 0ULL) ? 1 : 0;
}

// ---------------------------------------------------------------------------
// Setup: wtab[v][k] = sum_d emb[v,d] * W_w[k,d] + W_b[k]   (18 x 16, f32)
// ---------------------------------------------------------------------------
__global__ void wtab_kernel(const void* __restrict__ emb,
                            const void* __restrict__ W_w,
                            const void* __restrict__ W_b,
                            const int* __restrict__ flag,
                            float* __restrict__ wtab) {
    int tid = threadIdx.x;
    int isbf = flag[1];
    if (tid < VOCAB * DIM) {
        int v = tid >> 4, kk = tid & 15;
        float s = ldf(W_b, kk, isbf);
#pragma unroll
        for (int d = 0; d < DIM; ++d)
            s = fmaf(ldf(emb, v * DIM + d, isbf), ldf(W_w, kk * DIM + d, isbf), s);
        wtab[tid] = s;
    }
}

// DPP row-rotate (within 16-lane rows), compile-time control 0x120|N.
template <int CTRL>
__device__ __forceinline__ float ror_f(float v) {
    return __int_as_float(
        __builtin_amdgcn_mov_dpp(__float_as_int(v), CTRL, 0xF, 0xF, true));
}

// Fused a += ror_j(b) * u  and  a = ror_j(b) * u  (VOP2 + DPP, 1 inst each).
#define FMAC_ROR(A, B, U, N)                                              \
    asm("v_fmac_f32_dpp %0, %1, %2 row_ror:" #N                           \
        " row_mask:0xf bank_mask:0xf"                                     \
        : "+v"(A)                                                         \
        : "v"(B), "v"(U))
#define MUL_ROR(A, B, U, N)                                               \
    asm("v_mul_f32_dpp %0, %1, %2 row_ror:" #N                            \
        " row_mask:0xf bank_mask:0xf"                                     \
        : "=v"(A)                                                         \
        : "v"(B), "v"(U))

// Sum across the lane<->lane+32 pair (both lanes get the full sum).
__device__ __forceinline__ float pair_sum32(float p) {
#if __has_builtin(__builtin_amdgcn_permlane32_swap)
    typedef int i32x2 __attribute__((ext_vector_type(2)));
    i32x2 sw = __builtin_amdgcn_permlane32_swap(__float_as_int(p),
                                                __float_as_int(p), false, false);
    return __int_as_float(sw.x) + __int_as_float(sw.y);
#else
    return p + __shfl_xor(p, 32, 64);
#endif
}

#define WSTR 19    // wtabT row stride: gcd(19,32)=1 -> 16 lanes, 16 banks
#define WHIB 304   // hi-half zero-region base (16*19)
#define WZLEN 608  // rows 0..303 real, 304..607 zeros
#define SSTR 68    // slab element stride in words (16B-aligned, bank offset 4)

// ---------------------------------------------------------------------------
// Main RNN kernel (R17-validated folded-state 32-lane layout).
// State r = 1/(2^S+1):
//   S = scale*(wtab[tok][k]+rowsumU[k]) + sum_j (-2*scale*U[k][dj]) * r[dj]
// rows 0,1 = elems A,B terms 0-7; rows 2,3 = terms 8-15 (base ror:8).
// Halves summed via permlane32_swap. Inner product: fused VOP2+DPP asm.
// Tokens: wave-private double-buffered LDS slab, imm-offset broadcast reads.
// 512 thr/block, 256 blocks -> 2 waves/SIMD, free-running.
// ---------------------------------------------------------------------------
__global__ __launch_bounds__(512) void rnn_kernel(const int* __restrict__ x32,
                                                  const int* __restrict__ flag,
                                                  const float* __restrict__ wtab_g,
                                                  const void* __restrict__ U_w,
                                                  const void* __restrict__ head_w,
                                                  const void* __restrict__ head_b,
                                                  float* __restrict__ out) {
    __shared__ float wtabT[WZLEN];   // [k][v] stride 19, folded+prescaled
    __shared__ float sU[DIM * DIM];
    __shared__ float lds_h[16][DIM];
    __shared__ int slab[2][16 * SSTR];  // token slabs, wave-private slices

    const int tid = threadIdx.x;
    const int is64 = __builtin_amdgcn_readfirstlane(flag[0]);
    const int isbf = __builtin_amdgcn_readfirstlane(flag[1]);

    // Strided fills (never the guarded-single-store bug again).
    for (int i = tid; i < WZLEN; i += 512) {
        float val = 0.0f;
        int r = i / WSTR, v = i - r * WSTR;
        if (r < 16 && v < VOCAB) {
            float rs = 0.0f;
#pragma unroll
            for (int d = 0; d < DIM; ++d) rs += ldf(U_w, r * DIM + d, isbf);
            val = (wtab_g[v * DIM + r] + rs) * TWO_LOG2E;  // transposed + folded
        }
        wtabT[i] = val;
    }
    for (int i = tid; i < DIM * DIM; i += 512) sU[i] = ldf(U_w, i, isbf);
    __syncthreads();  // the only block-wide barrier until the head

    const int lane = tid & 63;
    const int wave = tid >> 6;
    const int row = lane >> 4;              // 0..3
    const int k = lane & 15;                // output dim owned by this lane
    const int half = row >> 1;              // 0: terms 0-7; 1: terms 8-15
    const int e = (wave << 1) | (row & 1);  // element within block
    const bool lo32 = (lane < 32);
    const int gelem = (blockIdx.x << 4) | e;

    // Probe DPP ror direction (validated R12-R17).
    int p = __builtin_amdgcn_mov_dpp(k, 0x121, 0xF, 0xF, true);
    int c = (p - k) & 15;

    // ur2[j] = -2 * scale * U[k][(k + (j + 8*half)*c) & 15].
    float ur2[8];
#pragma unroll
    for (int j = 0; j < 8; ++j)
        ur2[j] = sU[(k << 4) | ((k + (j + 8 * half) * c) & 15)] *
                 (-2.0f * TWO_LOG2E);

    // wtab row base (float idx): lo half -> real row k; hi half -> zeros.
    const int wb = k * WSTR + half * WHIB;

    // Lane's token slots in global: steps 4k..4k+3 of each 64-step blk.
    const size_t tokbase = (size_t)gelem * TLEN + (k << 2);

    int* cur = &slab[0][e * SSTR];
    int* nxt = &slab[1][e * SSTR];

    int4 g;
#define LOADG(G, B)                                                           \
    if (lo32) {                                                               \
        if (is64) {                                                           \
            const int* pp = x32 + ((tokbase + ((size_t)(B) << 6)) << 1);      \
            int4 a = *(const int4*)pp;                                        \
            int4 bq = *(const int4*)(pp + 4);                                 \
            G = make_int4(a.x, a.z, bq.x, bq.z);                              \
        } else {                                                              \
            G = *(const int4*)(x32 + tokbase + ((size_t)(B) << 6));           \
        }                                                                     \
    }

    // Prologue: slab0 <- blk0; gcur <- blk1; prime pipeline regs.
    LOADG(g, 0)
    if (lo32) *(int4*)(cur + (k << 2)) = g;
    int4 gcur;
    LOADG(gcur, 1)

    int tk0 = cur[0], tk1 = cur[1];
    int t2 = cur[2], t3 = cur[3];
    float w0 = wtabT[wb + tk0], w1 = wtabT[wb + tk1];

    float rst = 0.5f;  // r-state for h0 = 0

    for (int b = 0; b < NBLK; ++b) {
        // Write next slab from gcur (loaded one blk ago), refill gcur.
        if (lo32) *(int4*)(nxt + (k << 2)) = gcur;
        const int nb2 = (b + 2 < NBLK) ? b + 2 : NBLK - 1;
        LOADG(gcur, nb2)

#pragma unroll
        for (int s = 0; s < 64; ++s) {
            // Token 4 ahead (imm-offset broadcast read), wtab value 2 ahead.
            int t4 = (s + 4 < 64) ? cur[s + 4] : nxt[s - 60];
            float w2 = wtabT[wb + t2];

            float r8 = ror_f<0x128>(rst);
            float bb = lo32 ? rst : r8;  // terms 0-7 use r; 8-15 use ror8(r)

            float a0 = w0;  // w0 = 0 for hi half via zero rows
            float a1;
            a0 = fmaf(ur2[0], bb, a0);
            MUL_ROR(a1, bb, ur2[1], 1);
            FMAC_ROR(a0, bb, ur2[2], 2);
            FMAC_ROR(a1, bb, ur2[3], 3);
            FMAC_ROR(a0, bb, ur2[4], 4);
            FMAC_ROR(a1, bb, ur2[5], 5);
            FMAC_ROR(a0, bb, ur2[6], 6);
            FMAC_ROR(a1, bb, ur2[7], 7);

            float S = pair_sum32(a0 + a1);
            rst = __builtin_amdgcn_rcpf(__builtin_amdgcn_exp2f(S) + 1.0f);

            w0 = w1;
            w1 = w2;
            t2 = t3;
            t3 = t4;
        }
        int* tmp = cur;
        cur = nxt;
        nxt = tmp;
    }

    // Head: h = 1 - 2r; out[b,v] = h . head_w[v,:] + head_b[v], f32 store.
    if (lo32) lds_h[e][k] = fmaf(-2.0f, rst, 1.0f);
    __syncthreads();

    for (int i = tid; i < 16 * VOCAB; i += 512) {
        int ee = i / VOCAB;
        int v = i - ee * VOCAB;
        float s = ldf(head_b, v, isbf);
#pragma unroll
        for (int d = 0; d < DIM; ++d)
            s = fmaf(lds_h[ee][d], ldf(head_w, (v << 4) + d, isbf), s);
        out[(size_t)((blockIdx.x << 4) | ee) * VOCAB + v] = s;
    }
}

extern "C" void kernel_launch(void* const* d_in, const int* in_sizes, int n_in,
                              void* d_out, int out_size, void* d_ws, size_t ws_size,
                              hipStream_t stream) {
    const int* x = (const int*)d_in[0];
    const void* emb = d_in[1];
    const void* W_w = d_in[2];
    const void* W_b = d_in[3];
    const void* U_w = d_in[4];
    const void* head_w = d_in[5];
    const void* head_b = d_in[6];

    float* wtab = (float*)d_ws;              // 288 floats
    int* flag = (int*)((char*)d_ws + 4096);  // [0]=tok is64, [1]=floats are bf16

    detect_tok<<<1, 64, 0, stream>>>(x, flag);
    detect_f<<<1, 64, 0, stream>>>((const unsigned short*)emb, flag);
    wtab_kernel<<<1, 320, 0, stream>>>(emb, W_w, W_b, flag, wtab);
    rnn_kernel<<<256, 512, 0, stream>>>(x, flag, wtab, U_w, head_w, head_b,
                                        (float*)d_out);
}

// Round 20
// 150.727 us; speedup vs baseline: 1.6879x; 1.2502x over previous
//
#include <hip/hip_runtime.h>
#include <cmath>

#define DIM 16
#define VOCAB 18
#define TLEN 2048
#define NBLK (TLEN / 64)
#define TWO_LOG2E 2.8853900817779268f  // 2*log2(e)

// Load float input element idx, from either a bf16 or f32 device buffer.
__device__ __forceinline__ float ldf(const void* p, int idx, int isbf) {
    if (isbf) {
        unsigned int w = ((const unsigned short*)p)[idx];
        return __uint_as_float(w << 16);
    }
    return ((const float*)p)[idx];
}

// ---------------------------------------------------------------------------
// Detector 1: token width. int64 tokens (0..17) have all odd 32-bit words 0.
// ---------------------------------------------------------------------------
__global__ void detect_tok(const int* __restrict__ x32, int* __restrict__ flag) {
    int v = 0;
    for (int j = threadIdx.x; j < 4096; j += 64) v |= x32[2 * j + 1];
    unsigned long long any = __ballot(v != 0);
    if (threadIdx.x == 0) flag[0] = (any == 0ULL) ? 1 : 0;
}

// ---------------------------------------------------------------------------
// Detector 2: float width. bf16 words of N(0,1) data have exponent in
// [90,140]; f32 lo-mantissa words are uniform random -> certain failure.
// ---------------------------------------------------------------------------
__global__ void detect_f(const unsigned short* __restrict__ emb16,
                         int* __restrict__ flag) {
    int bad = 0;
    for (int j = threadIdx.x; j < VOCAB * DIM; j += 64) {
        unsigned short w = emb16[j];
        int e = (w >> 7) & 0xFF;
        if (!((e >= 90 && e <= 140) || (w & 0x7FFF) == 0)) bad = 1;
    }
    unsigned long long anybad = __ballot(bad);
    if (threadIdx.x == 0) flag[1] = (anybad == 0ULL) ? 1 : 0;
}

// ---------------------------------------------------------------------------
// Setup: wtab[v][k] = sum_d emb[v,d] * W_w[k,d] + W_b[k]   (18 x 16, f32)
// ---------------------------------------------------------------------------
__global__ void wtab_kernel(const void* __restrict__ emb,
                            const void* __restrict__ W_w,
                            const void* __restrict__ W_b,
                            const int* __restrict__ flag,
                            float* __restrict__ wtab) {
    int tid = threadIdx.x;
    int isbf = flag[1];
    if (tid < VOCAB * DIM) {
        int v = tid >> 4, kk = tid & 15;
        float s = ldf(W_b, kk, isbf);
#pragma unroll
        for (int d = 0; d < DIM; ++d)
            s = fmaf(ldf(emb, v * DIM + d, isbf), ldf(W_w, kk * DIM + d, isbf), s);
        wtab[tid] = s;
    }
}

#define WSTR 19   // wtabT row stride: spreads 16 lanes over 16 banks
#define SSTR 68   // slab element stride (16B aligned; groups 4 banks apart)

// ---------------------------------------------------------------------------
// Main RNN kernel. 16 lanes per element, 4 elements/wave, full dot in-lane:
//   S_k = scale*(wtab[tok][k]+rowsumU[k]) + sum_j (-2*scale*U[k][dj])*r[dj]
//   r' = 1/(2^S+1)   (h = 1-2r folded into weights; R17/18-validated)
// MACs: 1 fmaf + ONE asm block: s_nop shield + 15 fused VOP2+DPP row_ror
// (fixed internal order -> no DPP can butt against the TRANS v_rcp write;
// R19's failure mode). Tokens: wave-private double-buffered LDS slab;
// w-value 3 steps ahead, token 6 ahead (register-rotated).
// 256 thr/block, 256 blocks -> 1024 waves = 1/SIMD.
// ---------------------------------------------------------------------------
__global__ __launch_bounds__(256) void rnn_kernel(const int* __restrict__ x32,
                                                  const int* __restrict__ flag,
                                                  const float* __restrict__ wtab_g,
                                                  const void* __restrict__ U_w,
                                                  const void* __restrict__ head_w,
                                                  const void* __restrict__ head_b,
                                                  float* __restrict__ out) {
    __shared__ float wtabT[16 * WSTR];  // [k][v] stride 19, folded+prescaled
    __shared__ float sU[DIM * DIM];
    __shared__ float lds_h[16][DIM];
    __shared__ int slab[2][16 * SSTR];  // token slabs, wave-private slices

    const int tid = threadIdx.x;
    const int is64 = __builtin_amdgcn_readfirstlane(flag[0]);
    const int isbf = __builtin_amdgcn_readfirstlane(flag[1]);

    // Strided fills (never the guarded-single-store bug again).
    for (int i = tid; i < 16 * WSTR; i += 256) {
        int r = i / WSTR, v = i - r * WSTR;
        float val = 0.0f;
        if (v < VOCAB) {
            float rs = 0.0f;
#pragma unroll
            for (int d = 0; d < DIM; ++d) rs += ldf(U_w, r * DIM + d, isbf);
            val = (wtab_g[v * DIM + r] + rs) * TWO_LOG2E;  // transposed+folded
        }
        wtabT[i] = val;
    }
    for (int i = tid; i < DIM * DIM; i += 256) sU[i] = ldf(U_w, i, isbf);
    __syncthreads();  // the only block-wide barrier until the head

    const int lane = tid & 63;
    const int wave = tid >> 6;
    const int g = lane >> 4;        // group (element) within wave
    const int k = lane & 15;        // output dim owned by this lane
    const int e = (wave << 2) | g;  // element within block
    const int gelem = (blockIdx.x << 4) | e;

    // Probe DPP ror direction (validated R12-R18).
    int p = __builtin_amdgcn_mov_dpp(k, 0x121, 0xF, 0xF, true);
    int c = (p - k) & 15;

    // ur2[j] = -2 * scale * U[k][(k + j*c) & 15], j = 0..15 (full dot).
    float ur2[16];
#pragma unroll
    for (int j = 0; j < 16; ++j)
        ur2[j] = sU[(k << 4) | ((k + j * c) & 15)] * (-2.0f * TWO_LOG2E);

    const int wb = k * WSTR;  // wtab row base (all lanes read real rows)

    // Lane's token slots in global: steps 4k..4k+3 of each 64-step blk.
    const size_t tokbase = (size_t)gelem * TLEN + (k << 2);

    int* cur = &slab[0][e * SSTR];
    int* nxt = &slab[1][e * SSTR];

    int4 g0;
#define LOADG(G, B)                                                           \
    {                                                                         \
        if (is64) {                                                           \
            const int* pp = x32 + ((tokbase + ((size_t)(B) << 6)) << 1);      \
            int4 a = *(const int4*)pp;                                        \
            int4 bq = *(const int4*)(pp + 4);                                 \
            G = make_int4(a.x, a.z, bq.x, bq.z);                              \
        } else {                                                              \
            G = *(const int4*)(x32 + tokbase + ((size_t)(B) << 6));           \
        }                                                                     \
    }

    // Prologue: slab0 <- blk0; gcur <- blk1; prime the pipelines.
    LOADG(g0, 0)
    *(int4*)(cur + (k << 2)) = g0;
    int4 gcur;
    LOADG(gcur, 1)

    int t3 = cur[3], t4 = cur[4], t5 = cur[5];
    float w0 = wtabT[wb + cur[0]];
    float w1 = wtabT[wb + cur[1]];
    float w2 = wtabT[wb + cur[2]];

    float rst = 0.5f;  // r-state for h0 = 0

    for (int b = 0; b < NBLK; ++b) {
        // Write next slab from gcur (loaded one blk ago), refill gcur.
        *(int4*)(nxt + (k << 2)) = gcur;
        const int nb2 = (b + 2 < NBLK) ? b + 2 : NBLK - 1;
        LOADG(gcur, nb2)

#pragma unroll
        for (int s = 0; s < 64; ++s) {
            // Token 6 ahead (imm-offset broadcast), w-value 3 ahead.
            int t6 = (s + 6 < 64) ? cur[s + 6] : nxt[s - 58];
            float w3 = wtabT[wb + t3];

            float a0 = fmaf(ur2[0], rst, w0);
            float a1, a2, a3;
            // One block: s_nop shields the asm DPPs from the v_rcp (TRANS)
            // write of rst; fixed order prevents scheduler adjacency.
            asm("s_nop 1\n\t"
                "v_mul_f32_dpp %[a1], %[r], %[u1] row_ror:1 row_mask:0xf bank_mask:0xf\n\t"
                "v_mul_f32_dpp %[a2], %[r], %[u2] row_ror:2 row_mask:0xf bank_mask:0xf\n\t"
                "v_mul_f32_dpp %[a3], %[r], %[u3] row_ror:3 row_mask:0xf bank_mask:0xf\n\t"
                "v_fmac_f32_dpp %[a0], %[r], %[u4] row_ror:4 row_mask:0xf bank_mask:0xf\n\t"
                "v_fmac_f32_dpp %[a1], %[r], %[u5] row_ror:5 row_mask:0xf bank_mask:0xf\n\t"
                "v_fmac_f32_dpp %[a2], %[r], %[u6] row_ror:6 row_mask:0xf bank_mask:0xf\n\t"
                "v_fmac_f32_dpp %[a3], %[r], %[u7] row_ror:7 row_mask:0xf bank_mask:0xf\n\t"
                "v_fmac_f32_dpp %[a0], %[r], %[u8] row_ror:8 row_mask:0xf bank_mask:0xf\n\t"
                "v_fmac_f32_dpp %[a1], %[r], %[u9] row_ror:9 row_mask:0xf bank_mask:0xf\n\t"
                "v_fmac_f32_dpp %[a2], %[r], %[u10] row_ror:10 row_mask:0xf bank_mask:0xf\n\t"
                "v_fmac_f32_dpp %[a3], %[r], %[u11] row_ror:11 row_mask:0xf bank_mask:0xf\n\t"
                "v_fmac_f32_dpp %[a0], %[r], %[u12] row_ror:12 row_mask:0xf bank_mask:0xf\n\t"
                "v_fmac_f32_dpp %[a1], %[r], %[u13] row_ror:13 row_mask:0xf bank_mask:0xf\n\t"
                "v_fmac_f32_dpp %[a2], %[r], %[u14] row_ror:14 row_mask:0xf bank_mask:0xf\n\t"
                "v_fmac_f32_dpp %[a3], %[r], %[u15] row_ror:15 row_mask:0xf bank_mask:0xf"
                : [a0] "+v"(a0), [a1] "=&v"(a1), [a2] "=&v"(a2), [a3] "=&v"(a3)
                : [r] "v"(rst), [u1] "v"(ur2[1]), [u2] "v"(ur2[2]),
                  [u3] "v"(ur2[3]), [u4] "v"(ur2[4]), [u5] "v"(ur2[5]),
                  [u6] "v"(ur2[6]), [u7] "v"(ur2[7]), [u8] "v"(ur2[8]),
                  [u9] "v"(ur2[9]), [u10] "v"(ur2[10]), [u11] "v"(ur2[11]),
                  [u12] "v"(ur2[12]), [u13] "v"(ur2[13]), [u14] "v"(ur2[14]),
                  [u15] "v"(ur2[15]));

            float S = (a0 + a1) + (a2 + a3);
            rst = __builtin_amdgcn_rcpf(__builtin_amdgcn_exp2f(S) + 1.0f);

            w0 = w1;
            w1 = w2;
            w2 = w3;
            t3 = t4;
            t4 = t5;
            t5 = t6;
        }
        int* tmp = cur;
        cur = nxt;
        nxt = tmp;
    }

    // Head: h = 1 - 2r; out[b,v] = h . head_w[v,:] + head_b[v], f32 store.
    lds_h[e][k] = fmaf(-2.0f, rst, 1.0f);
    __syncthreads();

    for (int i = tid; i < 16 * VOCAB; i += 256) {
        int ee = i / VOCAB;
        int v = i - ee * VOCAB;
        float s = ldf(head_b, v, isbf);
#pragma unroll
        for (int d = 0; d < DIM; ++d)
            s = fmaf(lds_h[ee][d], ldf(head_w, (v << 4) + d, isbf), s);
        out[(size_t)((blockIdx.x << 4) | ee) * VOCAB + v] = s;
    }
}

extern "C" void kernel_launch(void* const* d_in, const int* in_sizes, int n_in,
                              void* d_out, int out_size, void* d_ws, size_t ws_size,
                              hipStream_t stream) {
    const int* x = (const int*)d_in[0];
    const void* emb = d_in[1];
    const void* W_w = d_in[2];
    const void* W_b = d_in[3];
    const void* U_w = d_in[4];
    const void* head_w = d_in[5];
    const void* head_b = d_in[6];

    float* wtab = (float*)d_ws;              // 288 floats
    int* flag = (int*)((char*)d_ws + 4096);  // [0]=tok is64, [1]=floats are bf16

    detect_tok<<<1, 64, 0, stream>>>(x, flag);
    detect_f<<<1, 64, 0, stream>>>((const unsigned short*)emb, flag);
    wtab_kernel<<<1, 320, 0, stream>>>(emb, W_w, W_b, flag, wtab);
    rnn_kernel<<<256, 256, 0, stream>>>(x, flag, wtab, U_w, head_w, head_b,
                                        (float*)d_out);
}